// Round 3
// baseline (550.711 us; speedup 1.0000x reference)
//
#include <hip/hip_runtime.h>
#include <cstdint>
#include <cstddef>

// ---- problem constants ----
#define D_MODEL 2048
#define D_INNER 4096
#define D_IN2   8192
#define D_STATE 16
#define D_CONVK 4
#define DT_RANK 128
#define BATCH   2
#define SEQLEN  1024
#define BL      (BATCH*SEQLEN)
#define XDBL_N  (DT_RANK + 2*D_STATE)   // 160
#define XPW_NPAD 256
#define XPROJ_SPLITS 8
#define OUT_SPLITS 2

// chunked-scan constants
#define NCHUNK  16
#define LCHUNK  (SEQLEN/NCHUNK)         // 64
#define CHW     (BATCH*D_INNER*D_STATE) // 131072

// fused-cast segment block counts (256 thr/block, 1 uint4 out/thread)
#define NB_HID   2048
#define NB_IPW   8192
#define NB_XPW   320
#define NB_XPWZ  192
#define NB_DTW   256
#define NB_OPW   4096
#define NB_XDBLZ 320

typedef short  s8v  __attribute__((ext_vector_type(8)));
typedef float  f4v  __attribute__((ext_vector_type(4)));

__device__ __forceinline__ float softplus_f(float v) {
    return (v > 20.f) ? v : log1pf(__expf(v));
}
__device__ __forceinline__ float silu_f(float v) {
    return v / (1.f + __expf(-v));
}
__device__ __forceinline__ float bf2f(short s) {
    return __uint_as_float(((uint32_t)(uint16_t)s) << 16);
}
__device__ __forceinline__ uint16_t f2bf(float f) {
    uint32_t u = __float_as_uint(f);
    return (uint16_t)((u + 0x7FFFu + ((u >> 16) & 1u)) >> 16);
}
__device__ __forceinline__ uint32_t packbf(float lo, float hi) {
    return ((uint32_t)f2bf(hi) << 16) | (uint32_t)f2bf(lo);
}
__device__ __forceinline__ float quad_sum(float p) {
    p += __int_as_float(__builtin_amdgcn_update_dpp(
            0, __float_as_int(p), 0xB1, 0xF, 0xF, true));
    p += __int_as_float(__builtin_amdgcn_update_dpp(
            0, __float_as_int(p), 0x4E, 0xF, 0xF, true));
    return p;
}

#define GLD16(gp, lp)                                                          \
    __builtin_amdgcn_global_load_lds(                                          \
        (const __attribute__((address_space(1))) void*)(gp),                   \
        (__attribute__((address_space(3))) void*)(lp), 16, 0, 0)

// ---- fused: all fp32->bf16 casts + zero-fills, one dispatch ----
__global__ __launch_bounds__(256)
void k_cast_all(const float* __restrict__ s0, uint32_t* __restrict__ d0,
                const float* __restrict__ s1, uint32_t* __restrict__ d1,
                const float* __restrict__ s2, uint32_t* __restrict__ d2,
                const float* __restrict__ s3, uint32_t* __restrict__ d3,
                const float* __restrict__ s4, uint32_t* __restrict__ d4,
                uint32_t* __restrict__ z0, uint32_t* __restrict__ z1)
{
    int blk = blockIdx.x;
    const float* src = nullptr; uint32_t* dst; int base; int zero = 0;
    if      (blk < NB_HID) { src = s0; dst = d0; base = blk; }
    else if ((blk -= NB_HID)  < NB_IPW)  { src = s1; dst = d1; base = blk; }
    else if ((blk -= NB_IPW)  < NB_XPW)  { src = s2; dst = d2; base = blk; }
    else if ((blk -= NB_XPW)  < NB_XPWZ) { dst = z0; base = blk; zero = 1; }
    else if ((blk -= NB_XPWZ) < NB_DTW)  { src = s3; dst = d3; base = blk; }
    else if ((blk -= NB_DTW)  < NB_OPW)  { src = s4; dst = d4; base = blk; }
    else                                 { dst = z1; base = blk - NB_OPW; zero = 1; }
    const int i = base * 256 + threadIdx.x;
    if (zero) { ((uint4*)dst)[i] = make_uint4(0u, 0u, 0u, 0u); return; }
    const float4 a = ((const float4*)src)[i * 2];
    const float4 b = ((const float4*)src)[i * 2 + 1];
    uint4 o;
    o.x = packbf(a.x, a.y); o.y = packbf(a.z, a.w);
    o.z = packbf(b.x, b.y); o.w = packbf(b.z, b.w);
    ((uint4*)dst)[i] = o;
}

// ---- tiny cast: xdbl_f[:, 0:128] (fp32, ld 160) -> dtA_bf [BL][128] bf16 ----
__global__ __launch_bounds__(256)
void k_cast_dtA(const float* __restrict__ xdbl, uint32_t* __restrict__ dtA)
{
    const int i  = blockIdx.x * 256 + threadIdx.x;   // 32768 threads
    const int r  = i >> 4;
    const int c8 = (i & 15) * 8;
    const float* src = xdbl + (size_t)r * XDBL_N + c8;
    const float4 u = *(const float4*)src;
    const float4 v = *(const float4*)(src + 4);
    uint4 o;
    o.x = packbf(u.x, u.y); o.y = packbf(u.z, u.w);
    o.z = packbf(v.x, v.y); o.w = packbf(v.z, v.w);
    *(uint4*)&dtA[i * 4] = o;
}

// ---- bf16 MFMA GEMM body: C[m,n] = sum_k A[m,k]*W[n,k], BK=64, swizzled ----
// EPI: 0 = fp32 store to slice blockIdx.z (LDS-coalesced),
//      2 = bf16 scatter store (tail hidden under deep K loop),
//      3 = fp32 atomicAdd,
//      4 = fp32 LDS-coalesced store of softplus(acc + bias[col]).
// EPI 0/4 route the MFMA-layout acc through a [64][132] LDS tile and emit
// 512B-contiguous float4 runs: the raw 64B-chunk scatter measured only
// ~360 GB/s effective write BW (dt kernel 125 us, all pipes idle, WRITE_SIZE
// invariant across two structurally different versions -> store-drain bound).
template<int EPI>
__device__ __forceinline__
void gemm_body(const short* __restrict__ A, int lda,
               const short* __restrict__ W, int ldw,
               void* __restrict__ Cv, int ldc, int M, int kchunk,
               const float* __restrict__ bias)
{
    __shared__ short sA[128 * 64];
    __shared__ short sW[128 * 64];

    const int tid = threadIdx.x;
    const int w   = tid >> 6;
    const int L   = tid & 63;
    const int bm  = blockIdx.y * 128;
    const int bn  = blockIdx.x * 128;
    const int k0  = blockIdx.z * kchunk;

    const int rsub = L >> 3;
    const int c8   = (((L & 7) - rsub) & 7) * 8;
    const short* Ag[4]; const short* Wg[4];
#pragma unroll
    for (int j = 0; j < 4; j++) {
        Ag[j] = A + (size_t)(bm + w * 32 + j * 8 + rsub) * lda + c8 + k0;
        Wg[j] = W + (size_t)(bn + w * 32 + j * 8 + rsub) * ldw + c8 + k0;
    }

    const int wm = (w >> 1) * 64;
    const int wn = (w & 1) * 64;
    const int cl = L & 15;
    const int qd = L >> 4;

    f4v acc[4][4];
#pragma unroll
    for (int i = 0; i < 4; i++)
#pragma unroll
        for (int j = 0; j < 4; j++) acc[i][j] = (f4v){0.f, 0.f, 0.f, 0.f};

    for (int k = 0; k < kchunk; k += 64) {
#pragma unroll
        for (int j = 0; j < 4; j++)
            GLD16(Ag[j] + k, &sA[(w * 32 + j * 8) * 64]);
#pragma unroll
        for (int j = 0; j < 4; j++)
            GLD16(Wg[j] + k, &sW[(w * 32 + j * 8) * 64]);
        __syncthreads();
#pragma unroll
        for (int kk = 0; kk < 2; kk++) {
            const int sl = ((kk * 4 + qd + cl) & 7) * 8;
            s8v a[4], b[4];
#pragma unroll
            for (int mt = 0; mt < 4; mt++)
                a[mt] = *(const s8v*)&sA[(wm + mt * 16 + cl) * 64 + sl];
#pragma unroll
            for (int nt = 0; nt < 4; nt++)
                b[nt] = *(const s8v*)&sW[(wn + nt * 16 + cl) * 64 + sl];
#pragma unroll
            for (int mt = 0; mt < 4; mt++)
#pragma unroll
                for (int nt = 0; nt < 4; nt++)
                    acc[mt][nt] = __builtin_amdgcn_mfma_f32_16x16x32_bf16(
                        a[mt], b[nt], acc[mt][nt], 0, 0, 0);
        }
        __syncthreads();
    }

    if constexpr (EPI == 0 || EPI == 4) {
        // ---- LDS-transposed coalesced fp32 epilogue, 2 halves of 64 rows ----
        __shared__ float sC[64][132];
        float* Cf = (float*)Cv;
        if constexpr (EPI == 0) Cf += (size_t)blockIdx.z * M * ldc;
#pragma unroll
        for (int half = 0; half < 2; half++) {
            __syncthreads();
            if (wm == half * 64) {
#pragma unroll
                for (int mt = 0; mt < 4; mt++)
#pragma unroll
                    for (int nt = 0; nt < 4; nt++)
#pragma unroll
                        for (int r = 0; r < 4; r++)
                            sC[mt * 16 + qd * 4 + r][wn + nt * 16 + cl] =
                                acc[mt][nt][r];
            }
            __syncthreads();
#pragma unroll
            for (int it = 0; it < 8; it++) {
                const int f4  = it * 256 + tid;
                const int row = f4 >> 5;          // lanes 0-31 -> one full row
                const int c4  = (f4 & 31) * 4;    // 512B contiguous per row
                float4 v = *(const float4*)&sC[row][c4];
                if constexpr (EPI == 4) {
                    const float4 bb = *(const float4*)&bias[bn + c4];
                    v.x = softplus_f(v.x + bb.x);
                    v.y = softplus_f(v.y + bb.y);
                    v.z = softplus_f(v.z + bb.z);
                    v.w = softplus_f(v.w + bb.w);
                }
                *(float4*)&Cf[(size_t)(bm + half * 64 + row) * ldc + bn + c4] = v;
            }
        }
    } else {
        float* Cf = (float*)Cv;
        short* Cs = (short*)Cv;
#pragma unroll
        for (int mt = 0; mt < 4; mt++) {
            const int row0 = bm + wm + mt * 16 + qd * 4;
#pragma unroll
            for (int nt = 0; nt < 4; nt++) {
                const int col = bn + wn + nt * 16 + cl;
                if (EPI == 3 && col >= XDBL_N) continue;
#pragma unroll
                for (int r = 0; r < 4; r++) {
                    const float v = acc[mt][nt][r];
                    if (EPI == 2)
                        Cs[(size_t)(row0 + r) * ldc + col] = (short)f2bf(v);
                    else
                        atomicAdd(&Cf[(size_t)(row0 + r) * ldc + col], v);
                }
            }
        }
    }
}

// named entry points (profiling visibility)
__global__ __launch_bounds__(256)
void k_gemm_inproj(const short* A, const short* W, short* C)
{ gemm_body<2>(A, D_MODEL, W, D_MODEL, C, D_IN2, BL, D_MODEL, nullptr); }

__global__ __launch_bounds__(256)
void k_gemm_xproj(const short* A, const short* W, float* C)
{ gemm_body<3>(A, D_INNER, W, D_INNER, C, XDBL_N, BL, D_INNER / XPROJ_SPLITS, nullptr); }

__global__ __launch_bounds__(256)
void k_gemm_outproj(const short* A, const short* W, float* C)
{ gemm_body<0>(A, D_INNER, W, D_INNER, C, D_MODEL, BL, D_INNER / OUT_SPLITS, nullptr); }

// dt_proj: dt = softplus(dtA_bf @ dtw_bf^T + bias), K=128, coalesced epilogue
__global__ __launch_bounds__(256)
void k_gemm_dt(const short* A, const short* W, const float* bias, float* C)
{ gemm_body<4>(A, DT_RANK, W, DT_RANK, C, D_INNER, BL, DT_RANK, bias); }

// ---- out_proj split-K reduce: out = P0 + P1 (float4) ----
__global__ __launch_bounds__(256)
void k_reduce_out(const float* __restrict__ P, float* __restrict__ out)
{
    const int i = blockIdx.x * 256 + threadIdx.x;   // float4 index
    const float4 a = ((const float4*)P)[i];
    const float4 b = ((const float4*)(P + (size_t)BL * D_MODEL))[i];
    ((float4*)out)[i] = make_float4(a.x + b.x, a.y + b.y, a.z + b.z, a.w + b.w);
}

// ---- causal depthwise conv1d (K=4) + SiLU ----
__global__ __launch_bounds__(256)
void k_conv(const short* __restrict__ xz_bf, const float* __restrict__ cw,
            const float* __restrict__ cb, short* __restrict__ x_bf)
{
    const int idx = blockIdx.x * 256 + threadIdx.x;
    const int d  = idx & (D_INNER - 1);
    const int bl = idx >> 12;
    const int l  = bl & (SEQLEN - 1);
    const int b  = bl >> 10;
    const short* xb = xz_bf + (size_t)b * SEQLEN * D_IN2 + d;
    float acc = cb[d];
#pragma unroll
    for (int k = 0; k < D_CONVK; k++) {
        const int ll = l + k - (D_CONVK - 1);
        if (ll >= 0) acc = fmaf(bf2f(xb[(size_t)ll * D_IN2]), cw[d * D_CONVK + k], acc);
    }
    x_bf[idx] = (short)f2bf(silu_f(acc));
}

// ================= chunked selective scan =================
__global__ __launch_bounds__(256)
void k_scan_p1(const short* __restrict__ x_bf, const float* __restrict__ dt,
               const float* __restrict__ xdbl, const float* __restrict__ A_log,
               float* __restrict__ h_end, float* __restrict__ Pprod)
{
    const int c   = blockIdx.y;
    const int ch0 = blockIdx.x * 64;
    const int b   = ch0 >> 12;
    const int d0  = ch0 & (D_INNER - 1);
    const int tid = threadIdx.x;
    const int g   = tid >> 2;
    const int q   = tid & 3;
    const int d   = d0 + g;

    const float4 Al = *(const float4*)&A_log[(d << 4) + (q << 2)];
    float An[4] = {-__expf(Al.x), -__expf(Al.y), -__expf(Al.z), -__expf(Al.w)};
    float h[4]  = {0.f, 0.f, 0.f, 0.f};
    float Pp[4] = {1.f, 1.f, 1.f, 1.f};

    __shared__ float s_x [16][68];
    __shared__ float s_dt[16][68];
    __shared__ float s_B [16][20];

    const int lt  = tid >> 4;
    const int ld4 = (tid & 15) * 4;

    for (int sub = 0; sub < LCHUNK / 16; sub++) {
        const int l0 = c * LCHUNK + sub * 16;
        const size_t bl = (size_t)(b * SEQLEN + l0 + lt);
        __syncthreads();
        {
            const short4 sx = *(const short4*)&x_bf[bl * D_INNER + d0 + ld4];
            const float4 dv = *(const float4*)&dt[bl * D_INNER + d0 + ld4];
            *(float4*)&s_x [lt][ld4] =
                make_float4(bf2f(sx.x), bf2f(sx.y), bf2f(sx.z), bf2f(sx.w));
            *(float4*)&s_dt[lt][ld4] = dv;
            if (tid < 64) {
                const int t2 = tid >> 2, k = (tid & 3) * 4;
                const size_t bl2 = (size_t)(b * SEQLEN + l0 + t2);
                *(float4*)&s_B[t2][k] =
                    *(const float4*)&xdbl[bl2 * XDBL_N + DT_RANK + k];
            }
        }
        __syncthreads();
#pragma unroll
        for (int t = 0; t < 16; t++) {
            const float xv  = s_x [t][g];
            const float dtv = s_dt[t][g];
            const float4 Bq = *(const float4*)&s_B[t][q * 4];
            const float Bv[4] = {Bq.x, Bq.y, Bq.z, Bq.w};
            const float dtx = dtv * xv;
#pragma unroll
            for (int j = 0; j < 4; j++) {
                const float dA = __expf(dtv * An[j]);
                h[j]  = fmaf(h[j], dA, dtx * Bv[j]);
                Pp[j] *= dA;
            }
        }
    }
    const size_t i0 = (size_t)c * CHW + (((size_t)(b * D_INNER + d)) << 4) + (q << 2);
    *(float4*)&h_end[i0] = make_float4(h[0], h[1], h[2], h[3]);
    *(float4*)&Pprod[i0] = make_float4(Pp[0], Pp[1], Pp[2], Pp[3]);
}

__global__ __launch_bounds__(256)
void k_scan_p3(const short* __restrict__ x_bf, short* __restrict__ y_bf,
               const float* __restrict__ dt, const float* __restrict__ xdbl,
               const short* __restrict__ xz_bf, const float* __restrict__ A_log,
               const float* __restrict__ Dvec,
               const float* __restrict__ h_end, const float* __restrict__ Pbuf)
{
    const int c   = blockIdx.y;
    const int ch0 = blockIdx.x * 64;
    const int b   = ch0 >> 12;
    const int d0  = ch0 & (D_INNER - 1);
    const int tid = threadIdx.x;
    const int g   = tid >> 2;
    const int q   = tid & 3;
    const int d   = d0 + g;

    const float4 Al = *(const float4*)&A_log[(d << 4) + (q << 2)];
    float An[4] = {-__expf(Al.x), -__expf(Al.y), -__expf(Al.z), -__expf(Al.w)};
    const float Dd = Dvec[d];

    float h[4] = {0.f, 0.f, 0.f, 0.f};
    const size_t base = (((size_t)(b * D_INNER + d)) << 4) + (q << 2);
    for (int j = 0; j < c; j++) {
        const float4 he = *(const float4*)&h_end[(size_t)j * CHW + base];
        const float4 Pp = *(const float4*)&Pbuf [(size_t)j * CHW + base];
        h[0] = fmaf(Pp.x, h[0], he.x);
        h[1] = fmaf(Pp.y, h[1], he.y);
        h[2] = fmaf(Pp.z, h[2], he.z);
        h[3] = fmaf(Pp.w, h[3], he.w);
    }

    __shared__ float s_x [16][68];
    __shared__ float s_dt[16][68];
    __shared__ float s_z [16][68];
    __shared__ float s_B [16][20];
    __shared__ float s_C [16][20];

    const int lt  = tid >> 4;
    const int ld4 = (tid & 15) * 4;

    for (int sub = 0; sub < LCHUNK / 16; sub++) {
        const int l0 = c * LCHUNK + sub * 16;
        const size_t bl = (size_t)(b * SEQLEN + l0 + lt);
        __syncthreads();
        {
            const short4 sx = *(const short4*)&x_bf[bl * D_INNER + d0 + ld4];
            const float4 dv = *(const float4*)&dt[bl * D_INNER + d0 + ld4];
            const short4 zv = *(const short4*)&xz_bf[bl * D_IN2 + D_INNER + d0 + ld4];
            *(float4*)&s_x [lt][ld4] =
                make_float4(bf2f(sx.x), bf2f(sx.y), bf2f(sx.z), bf2f(sx.w));
            *(float4*)&s_dt[lt][ld4] = dv;
            *(float4*)&s_z [lt][ld4] =
                make_float4(bf2f(zv.x), bf2f(zv.y), bf2f(zv.z), bf2f(zv.w));
            if (tid < 128) {
                const int t2 = (tid & 63) >> 2, k = (tid & 3) * 4;
                const size_t bl2 = (size_t)(b * SEQLEN + l0 + t2);
                const int off = (tid < 64) ? 0 : D_STATE;
                const float4 v =
                    *(const float4*)&xdbl[bl2 * XDBL_N + DT_RANK + off + k];
                if (tid < 64) *(float4*)&s_B[t2][k] = v;
                else          *(float4*)&s_C[t2][k] = v;
            }
        }
        __syncthreads();
        const size_t orow = (size_t)(b * SEQLEN + l0);
#pragma unroll
        for (int t = 0; t < 16; t++) {
            const float xv  = s_x [t][g];
            const float dtv = s_dt[t][g];
            const float4 Bq = *(const float4*)&s_B[t][q * 4];
            const float4 Cq = *(const float4*)&s_C[t][q * 4];
            const float Bv[4] = {Bq.x, Bq.y, Bq.z, Bq.w};
            const float Cv[4] = {Cq.x, Cq.y, Cq.z, Cq.w};
            const float dtx = dtv * xv;
            float p = 0.f;
#pragma unroll
            for (int j = 0; j < 4; j++) {
                const float dA = __expf(dtv * An[j]);
                h[j] = fmaf(h[j], dA, dtx * Bv[j]);
                p = fmaf(h[j], Cv[j], p);
            }
            p = quad_sum(p);
            if (q == 0) {
                const float yv = fmaf(xv, Dd, p) * silu_f(s_z[t][g]);
                y_bf[(orow + t) * D_INNER + d] = (short)f2bf(yv);
            }
        }
    }
}

extern "C" void kernel_launch(void* const* d_in, const int* in_sizes, int n_in,
                              void* d_out, int out_size, void* d_ws, size_t ws_size,
                              hipStream_t stream)
{
    const float* hidden     = (const float*)d_in[0];
    const float* in_proj_w  = (const float*)d_in[1];
    const float* conv_w     = (const float*)d_in[2];
    const float* conv_b     = (const float*)d_in[3];
    const float* x_proj_w   = (const float*)d_in[4];
    const float* dt_proj_w  = (const float*)d_in[5];
    const float* dt_proj_b  = (const float*)d_in[6];
    const float* A_log      = (const float*)d_in[7];
    const float* Dvec       = (const float*)d_in[8];
    const float* out_proj_w = (const float*)d_in[9];
    float* out = (float*)d_out;

    // ---- workspace layout (stream-ordered aliasing, ~140.3 MB) ----
    const size_t MB = 1ull << 20;
    char* ws = (char*)d_ws;
    short* xz_bf   = (short*)(ws);                  // [0,32)   bf16 [BL,8192]
    short* x_bf    = (short*)(ws + 32 * MB);        // [32,48)  bf16 [BL,4096]
    short* ipw_bf  = (short*)(ws + 48 * MB);        // [48,80)  dead after in_proj
    short* y_bf    = (short*)(ws + 48 * MB);        // [48,64)  alias (phase3)
    float* h_end   = (float*)(ws + 64 * MB);        // [64,72)  alias (phase1)
    float* Pbuf    = (float*)(ws + 72 * MB);        // [72,80)  alias (phase1)
    short* hid_bf  = (short*)(ws + 80 * MB);        // [80,88)  dead after in_proj
    short* dtA_bf  = (short*)(ws + 80 * MB);        // alias: bf16 [BL,128] (0.5 MB)
    short* opw_bf  = (short*)(ws + 88 * MB);        // [88,104)
    float* dt_f32  = (float*)(ws + 104 * MB);       // [104,136) dead after p3
    float* op_part = (float*)(ws + 104 * MB);       // alias: out_proj partials 2x16MB
    short* xpw_bf  = (short*)(ws + 136 * MB);       // [136,138)
    short* dtw_bf  = (short*)(ws + 138 * MB);       // [138,139)
    float* xdbl_f  = (float*)(ws + 139 * MB);       // 1.25 MB, atomic target

    const dim3 blk(256);

    // 0) fused casts + zero-fills
    k_cast_all<<<dim3(NB_HID + NB_IPW + NB_XPW + NB_XPWZ + NB_DTW + NB_OPW + NB_XDBLZ),
                blk, 0, stream>>>(
        hidden, (uint32_t*)hid_bf, in_proj_w, (uint32_t*)ipw_bf,
        x_proj_w, (uint32_t*)xpw_bf, dt_proj_w, (uint32_t*)dtw_bf,
        out_proj_w, (uint32_t*)opw_bf,
        (uint32_t*)(xpw_bf + (size_t)XDBL_N * D_INNER),
        (uint32_t*)xdbl_f);

    // 1) in_proj -> xz_bf (bf16 epilogue)
    k_gemm_inproj<<<dim3(D_IN2 / 128, BL / 128, 1), blk, 0, stream>>>(
        hid_bf, ipw_bf, xz_bf);

    // 2) conv + SiLU -> x_bf
    k_conv<<<dim3((BL * D_INNER) / 256), blk, 0, stream>>>(
        xz_bf, conv_w, conv_b, x_bf);

    // 3) x_proj split-K=8: atomicAdd into xdbl_f
    k_gemm_xproj<<<dim3(XPW_NPAD / 128, BL / 128, XPROJ_SPLITS), blk, 0, stream>>>(
        x_bf, xpw_bf, xdbl_f);

    // 4) dt_proj: cast dt-columns of xdbl to bf16 once, then GEMM with
    //    LDS-coalesced epilogue (scatter stores measured ~360 GB/s eff.)
    k_cast_dtA<<<dim3(BL * DT_RANK / 8 / 256), blk, 0, stream>>>(
        xdbl_f, (uint32_t*)dtA_bf);
    k_gemm_dt<<<dim3(D_INNER / 128, BL / 128), blk, 0, stream>>>(
        dtA_bf, dtw_bf, dt_proj_b, dt_f32);

    // 5) chunked selective scan
    k_scan_p1<<<dim3(BATCH * D_INNER / 64, NCHUNK - 1), blk, 0, stream>>>(
        x_bf, dt_f32, xdbl_f, A_log, h_end, Pbuf);
    k_scan_p3<<<dim3(BATCH * D_INNER / 64, NCHUNK), blk, 0, stream>>>(
        x_bf, y_bf, dt_f32, xdbl_f, xz_bf, A_log, Dvec, h_end, Pbuf);

    // 6) out_proj split-K=2 -> partials (coalesced), then reduce into d_out
    k_gemm_outproj<<<dim3(D_MODEL / 128, BL / 128, OUT_SPLITS), blk, 0, stream>>>(
        y_bf, opw_bf, op_part);
    k_reduce_out<<<dim3(BL * D_MODEL / 4 / 256), blk, 0, stream>>>(op_part, out);
}

// Round 4
// 442.301 us; speedup vs baseline: 1.2451x; 1.2451x over previous
//
#include <hip/hip_runtime.h>
#include <cstdint>
#include <cstddef>

// ---- problem constants ----
#define D_MODEL 2048
#define D_INNER 4096
#define D_IN2   8192
#define D_STATE 16
#define D_CONVK 4
#define DT_RANK 128
#define BATCH   2
#define SEQLEN  1024
#define BL      (BATCH*SEQLEN)
#define XDBL_N  (DT_RANK + 2*D_STATE)   // 160
#define XPW_NPAD 256
#define XPROJ_SPLITS 8
#define OUT_SPLITS 2

// chunked-scan constants
#define NCHUNK  16
#define LCHUNK  (SEQLEN/NCHUNK)         // 64
#define CHW     (BATCH*D_INNER*D_STATE) // 131072

// fused-cast segment block counts (256 thr/block, 1 uint4 out/thread)
#define NB_HID   2048
#define NB_IPW   8192
#define NB_XPW   320
#define NB_XPWZ  192
#define NB_DTW   256
#define NB_OPW   4096
#define NB_XDBLZ 320

typedef short  s8v  __attribute__((ext_vector_type(8)));
typedef float  f4v  __attribute__((ext_vector_type(4)));

__device__ __forceinline__ float softplus_f(float v) {
    return (v > 20.f) ? v : log1pf(__expf(v));
}
__device__ __forceinline__ float silu_f(float v) {
    return v / (1.f + __expf(-v));
}
__device__ __forceinline__ float bf2f(short s) {
    return __uint_as_float(((uint32_t)(uint16_t)s) << 16);
}
__device__ __forceinline__ uint16_t f2bf(float f) {
    uint32_t u = __float_as_uint(f);
    return (uint16_t)((u + 0x7FFFu + ((u >> 16) & 1u)) >> 16);
}
__device__ __forceinline__ uint32_t packbf(float lo, float hi) {
    return ((uint32_t)f2bf(hi) << 16) | (uint32_t)f2bf(lo);
}
__device__ __forceinline__ float quad_sum(float p) {
    p += __int_as_float(__builtin_amdgcn_update_dpp(
            0, __float_as_int(p), 0xB1, 0xF, 0xF, true));
    p += __int_as_float(__builtin_amdgcn_update_dpp(
            0, __float_as_int(p), 0x4E, 0xF, 0xF, true));
    return p;
}

#define GLD16(gp, lp)                                                          \
    __builtin_amdgcn_global_load_lds(                                          \
        (const __attribute__((address_space(1))) void*)(gp),                   \
        (__attribute__((address_space(3))) void*)(lp), 16, 0, 0)

// ---- fused: all fp32->bf16 casts + zero-fills, one dispatch ----
__global__ __launch_bounds__(256)
void k_cast_all(const float* __restrict__ s0, uint32_t* __restrict__ d0,
                const float* __restrict__ s1, uint32_t* __restrict__ d1,
                const float* __restrict__ s2, uint32_t* __restrict__ d2,
                const float* __restrict__ s3, uint32_t* __restrict__ d3,
                const float* __restrict__ s4, uint32_t* __restrict__ d4,
                uint32_t* __restrict__ z0, uint32_t* __restrict__ z1)
{
    int blk = blockIdx.x;
    const float* src = nullptr; uint32_t* dst; int base; int zero = 0;
    if      (blk < NB_HID) { src = s0; dst = d0; base = blk; }
    else if ((blk -= NB_HID)  < NB_IPW)  { src = s1; dst = d1; base = blk; }
    else if ((blk -= NB_IPW)  < NB_XPW)  { src = s2; dst = d2; base = blk; }
    else if ((blk -= NB_XPW)  < NB_XPWZ) { dst = z0; base = blk; zero = 1; }
    else if ((blk -= NB_XPWZ) < NB_DTW)  { src = s3; dst = d3; base = blk; }
    else if ((blk -= NB_DTW)  < NB_OPW)  { src = s4; dst = d4; base = blk; }
    else                                 { dst = z1; base = blk - NB_OPW; zero = 1; }
    const int i = base * 256 + threadIdx.x;
    if (zero) { ((uint4*)dst)[i] = make_uint4(0u, 0u, 0u, 0u); return; }
    const float4 a = ((const float4*)src)[i * 2];
    const float4 b = ((const float4*)src)[i * 2 + 1];
    uint4 o;
    o.x = packbf(a.x, a.y); o.y = packbf(a.z, a.w);
    o.z = packbf(b.x, b.y); o.w = packbf(b.z, b.w);
    ((uint4*)dst)[i] = o;
}

// ---- tiny cast: xdbl_f[:, 0:128] (fp32, ld 160) -> dtA_bf [BL][128] bf16 ----
__global__ __launch_bounds__(256)
void k_cast_dtA(const float* __restrict__ xdbl, uint32_t* __restrict__ dtA)
{
    const int i  = blockIdx.x * 256 + threadIdx.x;   // 32768 threads
    const int r  = i >> 4;
    const int c8 = (i & 15) * 8;
    const float* src = xdbl + (size_t)r * XDBL_N + c8;
    const float4 u = *(const float4*)src;
    const float4 v = *(const float4*)(src + 4);
    uint4 o;
    o.x = packbf(u.x, u.y); o.y = packbf(u.z, u.w);
    o.z = packbf(v.x, v.y); o.w = packbf(v.z, v.w);
    *(uint4*)&dtA[i * 4] = o;
}

// ---- streaming softplus: dt_f32 = softplus(dt_raw + bias[d]) ----
// Isolation experiment (R4): three structurally different dt-GEMMs were all
// ~120-128 us with every pipe idle; the invariants were (a) the
// log1pf/exp epilogue on the store-dependence chain of a one-round
// dispatch, (b) the aliased output buffer. This pass removes both from
// the GEMM: pure streaming, 8192 blocks, float4 in/out.
__global__ __launch_bounds__(256)
void k_softplus(const float* __restrict__ raw, const float* __restrict__ bias,
                float* __restrict__ out)
{
    const int i  = blockIdx.x * 256 + threadIdx.x;    // float4 index
    const int d0 = (i & (D_INNER / 4 - 1)) * 4;
    const float4 v  = ((const float4*)raw)[i];
    const float4 bb = *(const float4*)&bias[d0];
    float4 o;
    o.x = softplus_f(v.x + bb.x);
    o.y = softplus_f(v.y + bb.y);
    o.z = softplus_f(v.z + bb.z);
    o.w = softplus_f(v.w + bb.w);
    ((float4*)out)[i] = o;
}

// ---- bf16 MFMA GEMM body: C[m,n] = sum_k A[m,k]*W[n,k], BK=64, swizzled ----
// EPI: 0 = fp32 LDS-coalesced store to slice blockIdx.z,
//      2 = bf16 scatter store (tail hidden under deep K loop),
//      3 = fp32 atomicAdd.
template<int EPI>
__device__ __forceinline__
void gemm_body(const short* __restrict__ A, int lda,
               const short* __restrict__ W, int ldw,
               void* __restrict__ Cv, int ldc, int M, int kchunk)
{
    __shared__ short sA[128 * 64];
    __shared__ short sW[128 * 64];

    const int tid = threadIdx.x;
    const int w   = tid >> 6;
    const int L   = tid & 63;
    const int bm  = blockIdx.y * 128;
    const int bn  = blockIdx.x * 128;
    const int k0  = blockIdx.z * kchunk;

    const int rsub = L >> 3;
    const int c8   = (((L & 7) - rsub) & 7) * 8;
    const short* Ag[4]; const short* Wg[4];
#pragma unroll
    for (int j = 0; j < 4; j++) {
        Ag[j] = A + (size_t)(bm + w * 32 + j * 8 + rsub) * lda + c8 + k0;
        Wg[j] = W + (size_t)(bn + w * 32 + j * 8 + rsub) * ldw + c8 + k0;
    }

    const int wm = (w >> 1) * 64;
    const int wn = (w & 1) * 64;
    const int cl = L & 15;
    const int qd = L >> 4;

    f4v acc[4][4];
#pragma unroll
    for (int i = 0; i < 4; i++)
#pragma unroll
        for (int j = 0; j < 4; j++) acc[i][j] = (f4v){0.f, 0.f, 0.f, 0.f};

    for (int k = 0; k < kchunk; k += 64) {
#pragma unroll
        for (int j = 0; j < 4; j++)
            GLD16(Ag[j] + k, &sA[(w * 32 + j * 8) * 64]);
#pragma unroll
        for (int j = 0; j < 4; j++)
            GLD16(Wg[j] + k, &sW[(w * 32 + j * 8) * 64]);
        __syncthreads();
#pragma unroll
        for (int kk = 0; kk < 2; kk++) {
            const int sl = ((kk * 4 + qd + cl) & 7) * 8;
            s8v a[4], b[4];
#pragma unroll
            for (int mt = 0; mt < 4; mt++)
                a[mt] = *(const s8v*)&sA[(wm + mt * 16 + cl) * 64 + sl];
#pragma unroll
            for (int nt = 0; nt < 4; nt++)
                b[nt] = *(const s8v*)&sW[(wn + nt * 16 + cl) * 64 + sl];
#pragma unroll
            for (int mt = 0; mt < 4; mt++)
#pragma unroll
                for (int nt = 0; nt < 4; nt++)
                    acc[mt][nt] = __builtin_amdgcn_mfma_f32_16x16x32_bf16(
                        a[mt], b[nt], acc[mt][nt], 0, 0, 0);
        }
        __syncthreads();
    }

    if constexpr (EPI == 0) {
        // ---- LDS-transposed coalesced fp32 epilogue, 2 halves of 64 rows ----
        __shared__ float sC[64][132];
        float* Cf = (float*)Cv + (size_t)blockIdx.z * M * ldc;
#pragma unroll
        for (int half = 0; half < 2; half++) {
            __syncthreads();
            if (wm == half * 64) {
#pragma unroll
                for (int mt = 0; mt < 4; mt++)
#pragma unroll
                    for (int nt = 0; nt < 4; nt++)
#pragma unroll
                        for (int r = 0; r < 4; r++)
                            sC[mt * 16 + qd * 4 + r][wn + nt * 16 + cl] =
                                acc[mt][nt][r];
            }
            __syncthreads();
#pragma unroll
            for (int it = 0; it < 8; it++) {
                const int f4  = it * 256 + tid;
                const int row = f4 >> 5;          // lanes 0-31 -> one full row
                const int c4  = (f4 & 31) * 4;    // 512B contiguous per row
                const float4 v = *(const float4*)&sC[row][c4];
                *(float4*)&Cf[(size_t)(bm + half * 64 + row) * ldc + bn + c4] = v;
            }
        }
    } else {
        float* Cf = (float*)Cv;
        short* Cs = (short*)Cv;
#pragma unroll
        for (int mt = 0; mt < 4; mt++) {
            const int row0 = bm + wm + mt * 16 + qd * 4;
#pragma unroll
            for (int nt = 0; nt < 4; nt++) {
                const int col = bn + wn + nt * 16 + cl;
                if (EPI == 3 && col >= XDBL_N) continue;
#pragma unroll
                for (int r = 0; r < 4; r++) {
                    const float v = acc[mt][nt][r];
                    if (EPI == 2)
                        Cs[(size_t)(row0 + r) * ldc + col] = (short)f2bf(v);
                    else
                        atomicAdd(&Cf[(size_t)(row0 + r) * ldc + col], v);
                }
            }
        }
    }
}

// named entry points (profiling visibility)
__global__ __launch_bounds__(256)
void k_gemm_inproj(const short* A, const short* W, short* C)
{ gemm_body<2>(A, D_MODEL, W, D_MODEL, C, D_IN2, BL, D_MODEL); }

__global__ __launch_bounds__(256)
void k_gemm_xproj(const short* A, const short* W, float* C)
{ gemm_body<3>(A, D_INNER, W, D_INNER, C, XDBL_N, BL, D_INNER / XPROJ_SPLITS); }

__global__ __launch_bounds__(256)
void k_gemm_outproj(const short* A, const short* W, float* C)
{ gemm_body<0>(A, D_INNER, W, D_INNER, C, D_MODEL, BL, D_INNER / OUT_SPLITS); }

// dt_proj GEMM only (no activation): dt_raw = dtA_bf @ dtw_bf^T, K=128
__global__ __launch_bounds__(256)
void k_gemm_dt(const short* A, const short* W, float* C)
{ gemm_body<0>(A, DT_RANK, W, DT_RANK, C, D_INNER, BL, DT_RANK); }

// ---- out_proj split-K reduce: out = P0 + P1 (float4) ----
__global__ __launch_bounds__(256)
void k_reduce_out(const float* __restrict__ P, float* __restrict__ out)
{
    const int i = blockIdx.x * 256 + threadIdx.x;   // float4 index
    const float4 a = ((const float4*)P)[i];
    const float4 b = ((const float4*)(P + (size_t)BL * D_MODEL))[i];
    ((float4*)out)[i] = make_float4(a.x + b.x, a.y + b.y, a.z + b.z, a.w + b.w);
}

// ---- causal depthwise conv1d (K=4) + SiLU ----
__global__ __launch_bounds__(256)
void k_conv(const short* __restrict__ xz_bf, const float* __restrict__ cw,
            const float* __restrict__ cb, short* __restrict__ x_bf)
{
    const int idx = blockIdx.x * 256 + threadIdx.x;
    const int d  = idx & (D_INNER - 1);
    const int bl = idx >> 12;
    const int l  = bl & (SEQLEN - 1);
    const int b  = bl >> 10;
    const short* xb = xz_bf + (size_t)b * SEQLEN * D_IN2 + d;
    float acc = cb[d];
#pragma unroll
    for (int k = 0; k < D_CONVK; k++) {
        const int ll = l + k - (D_CONVK - 1);
        if (ll >= 0) acc = fmaf(bf2f(xb[(size_t)ll * D_IN2]), cw[d * D_CONVK + k], acc);
    }
    x_bf[idx] = (short)f2bf(silu_f(acc));
}

// ================= chunked selective scan =================
__global__ __launch_bounds__(256)
void k_scan_p1(const short* __restrict__ x_bf, const float* __restrict__ dt,
               const float* __restrict__ xdbl, const float* __restrict__ A_log,
               float* __restrict__ h_end, float* __restrict__ Pprod)
{
    const int c   = blockIdx.y;
    const int ch0 = blockIdx.x * 64;
    const int b   = ch0 >> 12;
    const int d0  = ch0 & (D_INNER - 1);
    const int tid = threadIdx.x;
    const int g   = tid >> 2;
    const int q   = tid & 3;
    const int d   = d0 + g;

    const float4 Al = *(const float4*)&A_log[(d << 4) + (q << 2)];
    float An[4] = {-__expf(Al.x), -__expf(Al.y), -__expf(Al.z), -__expf(Al.w)};
    float h[4]  = {0.f, 0.f, 0.f, 0.f};
    float Pp[4] = {1.f, 1.f, 1.f, 1.f};

    __shared__ float s_x [16][68];
    __shared__ float s_dt[16][68];
    __shared__ float s_B [16][20];

    const int lt  = tid >> 4;
    const int ld4 = (tid & 15) * 4;

    for (int sub = 0; sub < LCHUNK / 16; sub++) {
        const int l0 = c * LCHUNK + sub * 16;
        const size_t bl = (size_t)(b * SEQLEN + l0 + lt);
        __syncthreads();
        {
            const short4 sx = *(const short4*)&x_bf[bl * D_INNER + d0 + ld4];
            const float4 dv = *(const float4*)&dt[bl * D_INNER + d0 + ld4];
            *(float4*)&s_x [lt][ld4] =
                make_float4(bf2f(sx.x), bf2f(sx.y), bf2f(sx.z), bf2f(sx.w));
            *(float4*)&s_dt[lt][ld4] = dv;
            if (tid < 64) {
                const int t2 = tid >> 2, k = (tid & 3) * 4;
                const size_t bl2 = (size_t)(b * SEQLEN + l0 + t2);
                *(float4*)&s_B[t2][k] =
                    *(const float4*)&xdbl[bl2 * XDBL_N + DT_RANK + k];
            }
        }
        __syncthreads();
#pragma unroll
        for (int t = 0; t < 16; t++) {
            const float xv  = s_x [t][g];
            const float dtv = s_dt[t][g];
            const float4 Bq = *(const float4*)&s_B[t][q * 4];
            const float Bv[4] = {Bq.x, Bq.y, Bq.z, Bq.w};
            const float dtx = dtv * xv;
#pragma unroll
            for (int j = 0; j < 4; j++) {
                const float dA = __expf(dtv * An[j]);
                h[j]  = fmaf(h[j], dA, dtx * Bv[j]);
                Pp[j] *= dA;
            }
        }
    }
    const size_t i0 = (size_t)c * CHW + (((size_t)(b * D_INNER + d)) << 4) + (q << 2);
    *(float4*)&h_end[i0] = make_float4(h[0], h[1], h[2], h[3]);
    *(float4*)&Pprod[i0] = make_float4(Pp[0], Pp[1], Pp[2], Pp[3]);
}

__global__ __launch_bounds__(256)
void k_scan_p3(const short* __restrict__ x_bf, short* __restrict__ y_bf,
               const float* __restrict__ dt, const float* __restrict__ xdbl,
               const short* __restrict__ xz_bf, const float* __restrict__ A_log,
               const float* __restrict__ Dvec,
               const float* __restrict__ h_end, const float* __restrict__ Pbuf)
{
    const int c   = blockIdx.y;
    const int ch0 = blockIdx.x * 64;
    const int b   = ch0 >> 12;
    const int d0  = ch0 & (D_INNER - 1);
    const int tid = threadIdx.x;
    const int g   = tid >> 2;
    const int q   = tid & 3;
    const int d   = d0 + g;

    const float4 Al = *(const float4*)&A_log[(d << 4) + (q << 2)];
    float An[4] = {-__expf(Al.x), -__expf(Al.y), -__expf(Al.z), -__expf(Al.w)};
    const float Dd = Dvec[d];

    float h[4] = {0.f, 0.f, 0.f, 0.f};
    const size_t base = (((size_t)(b * D_INNER + d)) << 4) + (q << 2);
    for (int j = 0; j < c; j++) {
        const float4 he = *(const float4*)&h_end[(size_t)j * CHW + base];
        const float4 Pp = *(const float4*)&Pbuf [(size_t)j * CHW + base];
        h[0] = fmaf(Pp.x, h[0], he.x);
        h[1] = fmaf(Pp.y, h[1], he.y);
        h[2] = fmaf(Pp.z, h[2], he.z);
        h[3] = fmaf(Pp.w, h[3], he.w);
    }

    __shared__ float s_x [16][68];
    __shared__ float s_dt[16][68];
    __shared__ float s_z [16][68];
    __shared__ float s_B [16][20];
    __shared__ float s_C [16][20];

    const int lt  = tid >> 4;
    const int ld4 = (tid & 15) * 4;

    for (int sub = 0; sub < LCHUNK / 16; sub++) {
        const int l0 = c * LCHUNK + sub * 16;
        const size_t bl = (size_t)(b * SEQLEN + l0 + lt);
        __syncthreads();
        {
            const short4 sx = *(const short4*)&x_bf[bl * D_INNER + d0 + ld4];
            const float4 dv = *(const float4*)&dt[bl * D_INNER + d0 + ld4];
            const short4 zv = *(const short4*)&xz_bf[bl * D_IN2 + D_INNER + d0 + ld4];
            *(float4*)&s_x [lt][ld4] =
                make_float4(bf2f(sx.x), bf2f(sx.y), bf2f(sx.z), bf2f(sx.w));
            *(float4*)&s_dt[lt][ld4] = dv;
            *(float4*)&s_z [lt][ld4] =
                make_float4(bf2f(zv.x), bf2f(zv.y), bf2f(zv.z), bf2f(zv.w));
            if (tid < 128) {
                const int t2 = (tid & 63) >> 2, k = (tid & 3) * 4;
                const size_t bl2 = (size_t)(b * SEQLEN + l0 + t2);
                const int off = (tid < 64) ? 0 : D_STATE;
                const float4 v =
                    *(const float4*)&xdbl[bl2 * XDBL_N + DT_RANK + off + k];
                if (tid < 64) *(float4*)&s_B[t2][k] = v;
                else          *(float4*)&s_C[t2][k] = v;
            }
        }
        __syncthreads();
        const size_t orow = (size_t)(b * SEQLEN + l0);
#pragma unroll
        for (int t = 0; t < 16; t++) {
            const float xv  = s_x [t][g];
            const float dtv = s_dt[t][g];
            const float4 Bq = *(const float4*)&s_B[t][q * 4];
            const float4 Cq = *(const float4*)&s_C[t][q * 4];
            const float Bv[4] = {Bq.x, Bq.y, Bq.z, Bq.w};
            const float Cv[4] = {Cq.x, Cq.y, Cq.z, Cq.w};
            const float dtx = dtv * xv;
            float p = 0.f;
#pragma unroll
            for (int j = 0; j < 4; j++) {
                const float dA = __expf(dtv * An[j]);
                h[j] = fmaf(h[j], dA, dtx * Bv[j]);
                p = fmaf(h[j], Cv[j], p);
            }
            p = quad_sum(p);
            if (q == 0) {
                const float yv = fmaf(xv, Dd, p) * silu_f(s_z[t][g]);
                y_bf[(orow + t) * D_INNER + d] = (short)f2bf(yv);
            }
        }
    }
}

extern "C" void kernel_launch(void* const* d_in, const int* in_sizes, int n_in,
                              void* d_out, int out_size, void* d_ws, size_t ws_size,
                              hipStream_t stream)
{
    const float* hidden     = (const float*)d_in[0];
    const float* in_proj_w  = (const float*)d_in[1];
    const float* conv_w     = (const float*)d_in[2];
    const float* conv_b     = (const float*)d_in[3];
    const float* x_proj_w   = (const float*)d_in[4];
    const float* dt_proj_w  = (const float*)d_in[5];
    const float* dt_proj_b  = (const float*)d_in[6];
    const float* A_log      = (const float*)d_in[7];
    const float* Dvec       = (const float*)d_in[8];
    const float* out_proj_w = (const float*)d_in[9];
    float* out = (float*)d_out;

    // ---- workspace layout (stream-ordered aliasing, ~140.3 MB) ----
    const size_t MB = 1ull << 20;
    char* ws = (char*)d_ws;
    short* xz_bf   = (short*)(ws);                  // [0,32)   bf16 [BL,8192]
    short* x_bf    = (short*)(ws + 32 * MB);        // [32,48)  bf16 [BL,4096]
    short* ipw_bf  = (short*)(ws + 48 * MB);        // [48,80)  dead after in_proj
    float* dt_raw  = (float*)(ws + 48 * MB);        // alias: [48,80) pre-act dt
    short* y_bf    = (short*)(ws + 48 * MB);        // alias (phase3, after softplus)
    float* h_end   = (float*)(ws + 64 * MB);        // [64,72)  alias (phase1)
    float* Pbuf    = (float*)(ws + 72 * MB);        // [72,80)  alias (phase1)
    short* hid_bf  = (short*)(ws + 80 * MB);        // [80,88)  dead after in_proj
    short* dtA_bf  = (short*)(ws + 80 * MB);        // alias: bf16 [BL,128] (0.5 MB)
    short* opw_bf  = (short*)(ws + 88 * MB);        // [88,104)
    float* dt_f32  = (float*)(ws + 104 * MB);       // [104,136) dead after p3
    float* op_part = (float*)(ws + 104 * MB);       // alias: out_proj partials 2x16MB
    short* xpw_bf  = (short*)(ws + 136 * MB);       // [136,138)
    short* dtw_bf  = (short*)(ws + 138 * MB);       // [138,139)
    float* xdbl_f  = (float*)(ws + 139 * MB);       // 1.25 MB, atomic target

    const dim3 blk(256);

    // 0) fused casts + zero-fills
    k_cast_all<<<dim3(NB_HID + NB_IPW + NB_XPW + NB_XPWZ + NB_DTW + NB_OPW + NB_XDBLZ),
                blk, 0, stream>>>(
        hidden, (uint32_t*)hid_bf, in_proj_w, (uint32_t*)ipw_bf,
        x_proj_w, (uint32_t*)xpw_bf, dt_proj_w, (uint32_t*)dtw_bf,
        out_proj_w, (uint32_t*)opw_bf,
        (uint32_t*)(xpw_bf + (size_t)XDBL_N * D_INNER),
        (uint32_t*)xdbl_f);

    // 1) in_proj -> xz_bf (bf16 epilogue)
    k_gemm_inproj<<<dim3(D_IN2 / 128, BL / 128, 1), blk, 0, stream>>>(
        hid_bf, ipw_bf, xz_bf);

    // 2) conv + SiLU -> x_bf
    k_conv<<<dim3((BL * D_INNER) / 256), blk, 0, stream>>>(
        xz_bf, conv_w, conv_b, x_bf);

    // 3) x_proj split-K=8: atomicAdd into xdbl_f
    k_gemm_xproj<<<dim3(XPW_NPAD / 128, BL / 128, XPROJ_SPLITS), blk, 0, stream>>>(
        x_bf, xpw_bf, xdbl_f);

    // 4) dt_proj, split for isolation: bf16 cast -> plain GEMM (fresh buffer,
    //    no transcendentals in epilogue) -> streaming bias+softplus pass.
    k_cast_dtA<<<dim3(BL * DT_RANK / 8 / 256), blk, 0, stream>>>(
        xdbl_f, (uint32_t*)dtA_bf);
    k_gemm_dt<<<dim3(D_INNER / 128, BL / 128, 1), blk, 0, stream>>>(
        dtA_bf, dtw_bf, dt_raw);
    k_softplus<<<dim3(BL * D_INNER / 4 / 256), blk, 0, stream>>>(
        dt_raw, dt_proj_b, dt_f32);

    // 5) chunked selective scan
    k_scan_p1<<<dim3(BATCH * D_INNER / 64, NCHUNK - 1), blk, 0, stream>>>(
        x_bf, dt_f32, xdbl_f, A_log, h_end, Pbuf);
    k_scan_p3<<<dim3(BATCH * D_INNER / 64, NCHUNK), blk, 0, stream>>>(
        x_bf, y_bf, dt_f32, xdbl_f, xz_bf, A_log, Dvec, h_end, Pbuf);

    // 6) out_proj split-K=2 -> partials (coalesced), then reduce into d_out
    k_gemm_outproj<<<dim3(D_MODEL / 128, BL / 128, OUT_SPLITS), blk, 0, stream>>>(
        y_bf, opw_bf, op_part);
    k_reduce_out<<<dim3(BL * D_MODEL / 4 / 256), blk, 0, stream>>>(op_part, out);
}